// Round 2
// baseline (265.925 us; speedup 1.0000x reference)
//
#include <hip/hip_runtime.h>

typedef unsigned int u32;
typedef unsigned short u16;
typedef unsigned char u8;

// ws layout: [0..3] absmax bits (u32), Wq at offset 64: [769][1024] u8
// column f (0..767): offset-binary q+128 of round(W_in[l][f] * 127/absmax)
// column 768: all zero bytes (dummy for list padding; contributes nothing)

__global__ __launch_bounds__(64) void init_amax(u32* __restrict__ a) {
    if (threadIdx.x == 0) a[0] = 0u;
}

__global__ __launch_bounds__(256) void absmax_k(const float* __restrict__ W,
                                                u32* __restrict__ a) {
    int idx = blockIdx.x * 256 + threadIdx.x;   // 0 .. 768*1024-1
    float v = fabsf(W[idx]);
#pragma unroll
    for (int d = 32; d >= 1; d >>= 1) v = fmaxf(v, __shfl_xor(v, d));
    if ((threadIdx.x & 63) == 0) atomicMax(a, __float_as_uint(v));
}

__global__ __launch_bounds__(256) void quant_k(const float* __restrict__ W_in,
                                               const u32* __restrict__ a,
                                               u8* __restrict__ Wq) {
    int idx = blockIdx.x * 256 + threadIdx.x;   // 0 .. 769*1024-1
    int f = idx >> 10;
    int l = idx & 1023;
    u8 q = 0;
    if (f < 768) {
        float s = 127.0f / __uint_as_float(a[0]);
        int qi = (int)rintf(W_in[l * 768 + f] * s);
        qi = qi < -127 ? -127 : (qi > 127 ? 127 : qi);
        q = (u8)(qi + 128);
    }
    Wq[idx] = q;
}

// ---------------------------------------------------------------------------
// Main: one wave per batch row. int8 gather, packed u16-lane accumulation.
// ---------------------------------------------------------------------------
__global__ __launch_bounds__(256) void nnue_fwd(
    const float* __restrict__ x,       // [B][768]
    const u8*    __restrict__ Wq,      // [769][1024] int8 offset-binary
    const u32*   __restrict__ amax,    // scale source
    const float* __restrict__ b_in,    // [1024]
    const float* __restrict__ W_h,     // [8][1024]
    const float* __restrict__ b_h,     // [8]
    const float* __restrict__ W_psqt,  // [768]
    float* __restrict__ out,           // [B]
    int B) {
    const int wave = threadIdx.x >> 6;
    const int lane = threadIdx.x & 63;
    const int row  = (blockIdx.x << 2) | wave;
    const int rc   = row < B ? row : B - 1;

    __shared__ __align__(8) u16 lists[4][32];

    // ---- 1. load x row, build compact active-feature list ---------------
    const float4* xr = (const float4*)(x + (size_t)rc * 768);
    float4 v0 = xr[lane];
    float4 v1 = xr[lane + 64];
    float4 v2 = xr[lane + 128];
    float xs[12] = {v0.x, v0.y, v0.z, v0.w,
                    v1.x, v1.y, v1.z, v1.w,
                    v2.x, v2.y, v2.z, v2.w};

    int tl = 0;
#pragma unroll
    for (int k = 0; k < 12; ++k) tl += (xs[k] != 0.0f);

    int incl = tl;
#pragma unroll
    for (int d = 1; d < 64; d <<= 1) {
        int t = __shfl_up(incl, d);
        if (lane >= d) incl += t;
    }
    int off = incl - tl;
    int cnt = __shfl(incl, 63);                 // actives, 1..32
    cnt = __builtin_amdgcn_readfirstlane(cnt);

    int o = off;
#pragma unroll
    for (int k = 0; k < 12; ++k) {
        if (xs[k] != 0.0f) {
            int feat = ((k >> 2) << 8) + (lane << 2) + (k & 3);
            lists[wave][o++] = (u16)feat;
        }
    }
    const int cntp = (cnt + 3) & ~3;            // padded to multiple of 4
    if (lane >= cnt && lane < cntp) lists[wave][lane] = 768;  // dummy col
    __syncthreads();

    const int bucket = (cnt - 1) >> 2;

    // ---- 2. gather int8 columns, packed 16-bit lane accumulation --------
    // accE[k]: low16 = elem 4k+0, high16 = elem 4k+2
    // accO[k]: low16 = elem 4k+1, high16 = elem 4k+3   (elems rel. lane*16)
    u32 accE[4] = {0, 0, 0, 0};
    u32 accO[4] = {0, 0, 0, 0};

    const u8* wl = Wq + (lane << 4);            // lane's 16-byte slice
    for (int g = 0; g < cntp; g += 4) {
        uint2 le = *(const uint2*)&lists[wave][g];   // 4 u16 indices
        u32 w01 = __builtin_amdgcn_readfirstlane(le.x);
        u32 w23 = __builtin_amdgcn_readfirstlane(le.y);
        int f0 = w01 & 0xffff, f1 = w01 >> 16;
        int f2 = w23 & 0xffff, f3 = w23 >> 16;
        uint4 c0 = *(const uint4*)(wl + (f0 << 10));
        uint4 c1 = *(const uint4*)(wl + (f1 << 10));
        uint4 c2 = *(const uint4*)(wl + (f2 << 10));
        uint4 c3 = *(const uint4*)(wl + (f3 << 10));
#define ACCW(k, ww)                                                         \
        accE[k] += __builtin_amdgcn_perm(0u, (ww), 0x0c020c00u);            \
        accO[k] += __builtin_amdgcn_perm(0u, (ww), 0x0c030c01u);
#define ACCC(c) ACCW(0, c.x) ACCW(1, c.y) ACCW(2, c.z) ACCW(3, c.w)
        ACCC(c0) ACCC(c1) ACCC(c2) ACCC(c3)
#undef ACCC
#undef ACCW
    }

    // psqt partial: lanes 0..cnt-1 each grab one active feature's weight
    float psqt = 0.0f;
    if (lane < cnt) psqt = W_psqt[(int)lists[wave][lane]];

    // ---- 3. decode + bias + clip + single-head dot + reduce -------------
    const float sc = __uint_as_float(amax[0]) * (1.0f / 127.0f);
    const int base = cnt << 7;                  // 128 * cnt (offset removal)

    float dot = psqt;
    const float4* bi = (const float4*)(b_in + (lane << 4));
    const float4* wh = (const float4*)(W_h + (bucket << 10) + (lane << 4));
#pragma unroll
    for (int q = 0; q < 4; ++q) {
        float4 b4 = bi[q];
        float4 w4 = wh[q];
        int e0 = (int)(accE[q] & 0xffffu) - base;
        int e1 = (int)(accO[q] & 0xffffu) - base;
        int e2 = (int)(accE[q] >> 16) - base;
        int e3 = (int)(accO[q] >> 16) - base;
        float h;
        h = fminf(fmaxf((float)e0 * sc + b4.x, 0.0f), 1.0f); dot += h * w4.x;
        h = fminf(fmaxf((float)e1 * sc + b4.y, 0.0f), 1.0f); dot += h * w4.y;
        h = fminf(fmaxf((float)e2 * sc + b4.z, 0.0f), 1.0f); dot += h * w4.z;
        h = fminf(fmaxf((float)e3 * sc + b4.w, 0.0f), 1.0f); dot += h * w4.w;
    }
#pragma unroll
    for (int d = 32; d >= 1; d >>= 1) dot += __shfl_xor(dot, d);

    if (lane == 0 && row < B) out[row] = dot + b_h[bucket];
}

extern "C" void kernel_launch(void* const* d_in, const int* in_sizes, int n_in,
                              void* d_out, int out_size, void* d_ws, size_t ws_size,
                              hipStream_t stream) {
    const float* x      = (const float*)d_in[0];
    const float* W_in   = (const float*)d_in[1];
    const float* b_in   = (const float*)d_in[2];
    const float* W_h    = (const float*)d_in[3];
    const float* b_h    = (const float*)d_in[4];
    const float* W_psqt = (const float*)d_in[5];
    float* out = (float*)d_out;

    u32* amax = (u32*)d_ws;
    u8*  Wq   = (u8*)d_ws + 64;   // 769*1024 bytes

    init_amax<<<1, 64, 0, stream>>>(amax);
    absmax_k<<<(768 * 1024) / 256, 256, 0, stream>>>(W_in, amax);
    quant_k<<<(769 * 1024) / 256, 256, 0, stream>>>(W_in, amax, Wq);

    int B = out_size;       // 65536
    int grid = (B + 3) / 4; // 4 rows (waves) per 256-thread block
    nnue_fwd<<<grid, 256, 0, stream>>>(x, Wq, amax, b_in, W_h, b_h, W_psqt, out, B);
}

// Round 3
// 138.023 us; speedup vs baseline: 1.9267x; 1.9267x over previous
//
#include <hip/hip_runtime.h>

typedef unsigned int u32;
typedef unsigned short u16;
typedef unsigned char u8;

// ws layout (bytes):
//   [0..3]      amax (float)
//   [64..1087]  256 partial maxima (float)
//   [2048..]    Wq: [769][1024] u8, column f = offset-binary q+128; col 768 = 0
#define WQ_OFF 2048

#define RFL(x) __builtin_amdgcn_readfirstlane(x)
#define PERM __builtin_amdgcn_perm

// ---------------------------------------------------------------------------
// absmax, stage 1: 256 blocks x 256 threads x 12 strided elems, no atomics
// ---------------------------------------------------------------------------
__global__ __launch_bounds__(256) void amax_stage1(const float* __restrict__ W,
                                                   float* __restrict__ part) {
    int t = blockIdx.x * 256 + threadIdx.x;
    float v = 0.0f;
#pragma unroll
    for (int k = 0; k < 12; ++k) v = fmaxf(v, fabsf(W[t + (k << 16)]));
#pragma unroll
    for (int d = 32; d >= 1; d >>= 1) v = fmaxf(v, __shfl_xor(v, d));
    __shared__ float sm[4];
    if ((threadIdx.x & 63) == 0) sm[threadIdx.x >> 6] = v;
    __syncthreads();
    if (threadIdx.x == 0)
        part[blockIdx.x] = fmaxf(fmaxf(sm[0], sm[1]), fmaxf(sm[2], sm[3]));
}

// absmax, stage 2: one block reduces the 256 partials
__global__ __launch_bounds__(256) void amax_stage2(const float* __restrict__ part,
                                                   float* __restrict__ amax) {
    float v = part[threadIdx.x];
#pragma unroll
    for (int d = 32; d >= 1; d >>= 1) v = fmaxf(v, __shfl_xor(v, d));
    __shared__ float sm[4];
    if ((threadIdx.x & 63) == 0) sm[threadIdx.x >> 6] = v;
    __syncthreads();
    if (threadIdx.x == 0)
        amax[0] = fmaxf(fmaxf(sm[0], sm[1]), fmaxf(sm[2], sm[3]));
}

// ---------------------------------------------------------------------------
// quantize: W_in [1024][768] f32 -> Wq [769][1024] u8 (offset-binary, transposed)
// ---------------------------------------------------------------------------
__global__ __launch_bounds__(256) void quant_k(const float* __restrict__ W_in,
                                               const float* __restrict__ amax,
                                               u8* __restrict__ Wq) {
    int idx = blockIdx.x * 256 + threadIdx.x;   // 0 .. 769*1024-1
    int f = idx >> 10;
    int l = idx & 1023;
    u8 q = 0;
    if (f < 768) {
        float s = 127.0f / amax[0];
        int qi = (int)rintf(W_in[l * 768 + f] * s);
        qi = qi < -127 ? -127 : (qi > 127 ? 127 : qi);
        q = (u8)(qi + 128);
    }
    Wq[idx] = q;
}

// ---------------------------------------------------------------------------
// Main: one wave per batch row. Fixed 32-column gather (padded with zero
// column 768), depth-1 software pipeline in groups of 8 columns.
// ---------------------------------------------------------------------------
__global__ __launch_bounds__(256) void nnue_fwd(
    const float* __restrict__ x,       // [B][768]
    const u8*    __restrict__ Wq,      // [769][1024]
    const float* __restrict__ amax,
    const float* __restrict__ b_in,    // [1024]
    const float* __restrict__ W_h,     // [8][1024]
    const float* __restrict__ b_h,     // [8]
    const float* __restrict__ W_psqt,  // [768]
    float* __restrict__ out,           // [B]
    int B) {
    const int wave = threadIdx.x >> 6;
    const int lane = threadIdx.x & 63;
    const int row  = (blockIdx.x << 2) | wave;
    const int rc   = row < B ? row : B - 1;

    __shared__ __align__(16) u16 lists[4][32];

    // ---- 1. load x row, build compact active-feature list ---------------
    const float4* xr = (const float4*)(x + (size_t)rc * 768);
    float4 v0 = xr[lane];
    float4 v1 = xr[lane + 64];
    float4 v2 = xr[lane + 128];
    float xs[12] = {v0.x, v0.y, v0.z, v0.w,
                    v1.x, v1.y, v1.z, v1.w,
                    v2.x, v2.y, v2.z, v2.w};

    int tl = 0;
#pragma unroll
    for (int k = 0; k < 12; ++k) tl += (xs[k] != 0.0f);

    int incl = tl;
#pragma unroll
    for (int d = 1; d < 64; d <<= 1) {
        int t = __shfl_up(incl, d);
        if (lane >= d) incl += t;
    }
    int off = incl - tl;
    int cnt = __shfl(incl, 63);                 // actives, 1..32
    cnt = RFL(cnt);

    int o = off;
#pragma unroll
    for (int k = 0; k < 12; ++k) {
        if (xs[k] != 0.0f) {
            int feat = ((k >> 2) << 8) + (lane << 2) + (k & 3);
            lists[wave][o++] = (u16)feat;
        }
    }
    if (lane >= cnt && lane < 32) lists[wave][lane] = 768;  // zero column pad
    __syncthreads();

    const int bucket = (cnt - 1) >> 2;

    // ---- 2. fixed 32-column int8 gather, packed u16-lane accumulation ---
    // accE[k]: low16 = elem 4k+0, high16 = elem 4k+2  (rel. lane*16)
    // accO[k]: low16 = elem 4k+1, high16 = elem 4k+3
    u32 accE[4] = {0, 0, 0, 0};
    u32 accO[4] = {0, 0, 0, 0};

    const u8* wl = Wq + (lane << 4);            // lane's 16-byte slice

    const uint4 La = *(const uint4*)&lists[wave][0];    // cols 0..7
    const uint4 Lb = *(const uint4*)&lists[wave][8];    // cols 8..15
    const uint4 Lc = *(const uint4*)&lists[wave][16];   // cols 16..23
    const uint4 Ld = *(const uint4*)&lists[wave][24];   // cols 24..31

#define LOADG(p, L)                                                         \
    { u32 _a = RFL((L).x), _b = RFL((L).y), _c = RFL((L).z), _d = RFL((L).w); \
      p##0 = *(const uint4*)(wl + ((size_t)(_a & 0xffffu) << 10));          \
      p##1 = *(const uint4*)(wl + ((size_t)(_a >> 16)     << 10));          \
      p##2 = *(const uint4*)(wl + ((size_t)(_b & 0xffffu) << 10));          \
      p##3 = *(const uint4*)(wl + ((size_t)(_b >> 16)     << 10));          \
      p##4 = *(const uint4*)(wl + ((size_t)(_c & 0xffffu) << 10));          \
      p##5 = *(const uint4*)(wl + ((size_t)(_c >> 16)     << 10));          \
      p##6 = *(const uint4*)(wl + ((size_t)(_d & 0xffffu) << 10));          \
      p##7 = *(const uint4*)(wl + ((size_t)(_d >> 16)     << 10)); }

#define ACCW(k, ww)                                                         \
    accE[k] += PERM(0u, (ww), 0x0c020c00u);                                 \
    accO[k] += PERM(0u, (ww), 0x0c030c01u);
#define ACCC(c) ACCW(0, c.x) ACCW(1, c.y) ACCW(2, c.z) ACCW(3, c.w)
#define ACC8(p) ACCC(p##0) ACCC(p##1) ACCC(p##2) ACCC(p##3)                 \
                ACCC(p##4) ACCC(p##5) ACCC(p##6) ACCC(p##7)

    uint4 a0, a1, a2, a3, a4, a5, a6, a7;
    uint4 b0, b1, b2, b3, b4, b5, b6, b7;

    LOADG(a, La)       // group 0 in flight
    LOADG(b, Lb)       // group 1 in flight
    ACC8(a)            // consume group 0
    LOADG(a, Lc)       // group 2 in flight
    ACC8(b)            // consume group 1
    LOADG(b, Ld)       // group 3 in flight
    ACC8(a)            // consume group 2
    ACC8(b)            // consume group 3

#undef ACC8
#undef ACCC
#undef ACCW
#undef LOADG

    // psqt partial: lanes 0..cnt-1 each grab one active feature's weight
    float psqt = 0.0f;
    if (lane < cnt) psqt = W_psqt[(int)lists[wave][lane]];

    // ---- 3. decode + bias + clip + single-head dot + reduce -------------
    const float sc = amax[0] * (1.0f / 127.0f);
    const int base = cnt << 7;                  // 128 * cnt offset removal

    float dot = psqt;
    const float4* bi = (const float4*)(b_in + (lane << 4));
    const float4* wh = (const float4*)(W_h + (bucket << 10) + (lane << 4));
#pragma unroll
    for (int q = 0; q < 4; ++q) {
        float4 b4 = bi[q];
        float4 w4 = wh[q];
        int e0 = (int)(accE[q] & 0xffffu) - base;
        int e1 = (int)(accO[q] & 0xffffu) - base;
        int e2 = (int)(accE[q] >> 16) - base;
        int e3 = (int)(accO[q] >> 16) - base;
        float h;
        h = fminf(fmaxf((float)e0 * sc + b4.x, 0.0f), 1.0f); dot += h * w4.x;
        h = fminf(fmaxf((float)e1 * sc + b4.y, 0.0f), 1.0f); dot += h * w4.y;
        h = fminf(fmaxf((float)e2 * sc + b4.z, 0.0f), 1.0f); dot += h * w4.z;
        h = fminf(fmaxf((float)e3 * sc + b4.w, 0.0f), 1.0f); dot += h * w4.w;
    }
#pragma unroll
    for (int d = 32; d >= 1; d >>= 1) dot += __shfl_xor(dot, d);

    if (lane == 0 && row < B) out[row] = dot + b_h[bucket];
}

extern "C" void kernel_launch(void* const* d_in, const int* in_sizes, int n_in,
                              void* d_out, int out_size, void* d_ws, size_t ws_size,
                              hipStream_t stream) {
    const float* x      = (const float*)d_in[0];
    const float* W_in   = (const float*)d_in[1];
    const float* b_in   = (const float*)d_in[2];
    const float* W_h    = (const float*)d_in[3];
    const float* b_h    = (const float*)d_in[4];
    const float* W_psqt = (const float*)d_in[5];
    float* out = (float*)d_out;

    float* amax = (float*)d_ws;
    float* part = (float*)((char*)d_ws + 64);
    u8*    Wq   = (u8*)d_ws + WQ_OFF;   // 769*1024 bytes

    amax_stage1<<<256, 256, 0, stream>>>(W_in, part);
    amax_stage2<<<1, 256, 0, stream>>>(part, amax);
    quant_k<<<(769 * 1024) / 256, 256, 0, stream>>>(W_in, amax, Wq);

    int B = out_size;       // 65536
    int grid = (B + 3) / 4; // 4 rows (waves) per 256-thread block
    nnue_fwd<<<grid, 256, 0, stream>>>(x, Wq, amax, b_in, W_h, b_h, W_psqt, out, B);
}